// Round 8
// baseline (269.090 us; speedup 1.0000x reference)
//
#include <hip/hip_runtime.h>
#include <math.h>
#include <stdint.h>

#define K_DIM 8192
#define M_ROWS 8192
#define NC 24
#define RB 4            // rows per block
#define T 512           // threads per block

typedef float f32x4 __attribute__((ext_vector_type(4)));

// ---------------------------------------------------------------------------
// Kernel 0: prepack W into per-lane-coalesced fragment order:
//   Wp[(c*24 + e*6 + u)*512 + t] = W[k][4u..4u+3],  k = c*2048 + 4t + e
// so the fused kernel's W loads are 16B/lane fully-coalesced L2 streams.
// 196608 floats = 49152 float4 -> 786 KB (L2-resident everywhere).
// ---------------------------------------------------------------------------
__global__ __launch_bounds__(256) void mhc_prepack_kernel(
    const float* __restrict__ W, f32x4* __restrict__ Wp)
{
    const int idx = blockIdx.x * 256 + threadIdx.x;   // float4 index, 0..49151
    const int t = idx & 511;
    const int g = idx >> 9;            // 0..95 = c*24 + e*6 + u
    const int u = g % 6;
    const int e = (g / 6) & 3;
    const int c = g / 24;
    const int k = c * 2048 + 4 * t + e;
    const float* wr = W + (size_t)k * 32 + 4 * u;
    f32x4 v = {wr[0], wr[1], wr[2], wr[3]};
    Wp[idx] = v;
}

// ---------------------------------------------------------------------------
// Fused kernel. Block = 512 thr (8 waves) owns RB=4 rows. One X read total.
//  Thread t register set x4[r][c] = X[row r][c*2048 + 4t .. 4t+3]:
//   - GEMM: thread's k-set {c*2048+4t+e} covers block K once across threads
//     -> W read once per block (coalesced Wp); acc[4][24] fp32 in VGPRs.
//   - Reduce: 6-step butterfly per (r,n), cross-wave via 3KB LDS.
//   - Sinkhorn/transform on wave 0 (lane = row*16 + s*4+i), params -> LDS.
//   - Apply: thread-local einsum from the SAME x4 regs; coalesced O stores.
// No LDS X, no MFMA, no barriers in the K loop. HBM = 256MB in + 256MB out.
// ---------------------------------------------------------------------------
__global__ __launch_bounds__(T, 2) void mhc_fused_kernel(
    const float* __restrict__ X, const f32x4* __restrict__ Wp,
    const float* __restrict__ ab, float* __restrict__ out)
{
    __shared__ float red[8][96];
    __shared__ float Hf[96];
    __shared__ float pbuf[RB][NC];

    const int t = threadIdx.x;
    const int l = t & 63;
    const int wv = t >> 6;
    const size_t rowbase = (size_t)blockIdx.x * RB;

    const f32x4* __restrict__ Xg = reinterpret_cast<const f32x4*>(X);

    // ---- load X tile into registers, chunk-major so chunk0 arrives first ----
    f32x4 x4[RB][4];   // [row][c]; all indexing below is compile-time
#pragma unroll
    for (int c = 0; c < 4; ++c)
#pragma unroll
        for (int r = 0; r < RB; ++r)
            x4[r][c] = Xg[(rowbase + r) * 2048 + c * 512 + t];

    // ---- GEMM phase: acc[r][n] += X[r][k] * W[k][n] over thread's k-set ----
    float acc[RB][NC];
#pragma unroll
    for (int r = 0; r < RB; ++r)
#pragma unroll
        for (int n = 0; n < NC; ++n) acc[r][n] = 0.f;

#pragma unroll
    for (int c = 0; c < 4; ++c) {
#pragma unroll
        for (int e = 0; e < 4; ++e) {
#pragma unroll
            for (int u = 0; u < 6; ++u) {
                const f32x4 w = Wp[(size_t)((c * 4 + e) * 6 + u) * 512 + t];
#pragma unroll
                for (int r = 0; r < RB; ++r) {
                    const float xv = x4[r][c][e];
                    acc[r][u * 4 + 0] = fmaf(xv, w[0], acc[r][u * 4 + 0]);
                    acc[r][u * 4 + 1] = fmaf(xv, w[1], acc[r][u * 4 + 1]);
                    acc[r][u * 4 + 2] = fmaf(xv, w[2], acc[r][u * 4 + 2]);
                    acc[r][u * 4 + 3] = fmaf(xv, w[3], acc[r][u * 4 + 3]);
                }
            }
        }
    }

    // ---- reduce: butterfly each (r,n) across the wave, then across waves ----
    float v1 = 0.f, v2 = 0.f;
#pragma unroll
    for (int fl = 0; fl < 96; ++fl) {
        float v = acc[fl / NC][fl % NC];      // fl is unroll-constant -> static
        v += __shfl_xor(v, 1);
        v += __shfl_xor(v, 2);
        v += __shfl_xor(v, 4);
        v += __shfl_xor(v, 8);
        v += __shfl_xor(v, 16);
        v += __shfl_xor(v, 32);
        if (l == fl) v1 = v;                  // fl in [0,64)
        if (l == fl - 64) v2 = v;             // fl in [64,96)
    }
    red[wv][l] = v1;
    if (l < 32) red[wv][64 + l] = v2;
    __syncthreads();

    if (t < 96) {
        float h = 0.f;
#pragma unroll
        for (int w = 0; w < 8; ++w) h += red[w][t];
        Hf[t] = h;
    }
    __syncthreads();

    // ---- transform + sinkhorn on wave 0 (4 rows in parallel) ----
    if (wv == 0) {
        const int row = l >> 4, idx = l & 15;
        float p = __expf(fmaf(ab[24], Hf[row * NC + idx], ab[idx]));

        if (l < 32) {
            const int rr = l >> 3, ci = 16 + (l & 7);
            const float sc = (ci < 20) ? ab[25] : ab[26];
            pbuf[rr][ci] = fmaf(sc, 1.f / (1.f + __expf(-Hf[rr * NC + ci])), ab[ci]);
        }

        // lane idx = s*4 + i; axis=-1 sum = xor 1,2 ; axis=-2 sum = xor 4,8
        for (int it = 0; it < 20; ++it) {
            float rs = p + __shfl_xor(p, 1);
            rs += __shfl_xor(rs, 2);
            p = p / rs;
            float cs = p + __shfl_xor(p, 4);
            cs += __shfl_xor(cs, 8);
            p = p / cs;
        }
        pbuf[row][idx] = p;
    }
    __syncthreads();

    // ---- pin X registers so the compiler cannot re-load/rematerialize ----
#pragma unroll
    for (int r = 0; r < RB; ++r)
#pragma unroll
        for (int c = 0; c < 4; ++c)
            asm volatile("" : "+v"(x4[r][c]));

    // ---- apply phase: thread-local einsum, coalesced stores ----
    f32x4* __restrict__ Og = reinterpret_cast<f32x4*>(out);
#pragma unroll
    for (int r = 0; r < RB; ++r) {
        float hre[4][4], hpr[4], hpo[4];
#pragma unroll
        for (int q = 0; q < 16; ++q) hre[q >> 2][q & 3] = pbuf[r][q];
#pragma unroll
        for (int q = 0; q < 4; ++q) hpr[q] = pbuf[r][16 + q];
#pragma unroll
        for (int q = 0; q < 4; ++q) hpo[q] = pbuf[r][20 + q];

        f32x4 y = hpr[0] * x4[r][0] + hpr[1] * x4[r][1] +
                  hpr[2] * x4[r][2] + hpr[3] * x4[r][3];

#pragma unroll
        for (int s = 0; s < 4; ++s) {
            f32x4 o = hpo[s] * y
                    + hre[s][0] * x4[r][0] + hre[s][1] * x4[r][1]
                    + hre[s][2] * x4[r][2] + hre[s][3] * x4[r][3];
            Og[(rowbase + r) * 2048 + s * 512 + t] = o;
        }
    }
}

extern "C" void kernel_launch(void* const* d_in, const int* in_sizes, int n_in,
                              void* d_out, int out_size, void* d_ws, size_t ws_size,
                              hipStream_t stream) {
    const float* X  = (const float*)d_in[0];
    const float* W  = (const float*)d_in[1];
    const float* ab = (const float*)d_in[2];
    float* out = (float*)d_out;
    f32x4* Wp = (f32x4*)d_ws;    // 786,432 bytes

    mhc_prepack_kernel<<<192, 256, 0, stream>>>(W, Wp);
    mhc_fused_kernel<<<M_ROWS / RB, T, 0, stream>>>(X, Wp, ab, out);
}

// Round 9
// 193.218 us; speedup vs baseline: 1.3927x; 1.3927x over previous
//
#include <hip/hip_runtime.h>
#include <math.h>
#include <stdint.h>

#define K_DIM 8192     // S*DIM
#define D_DIM 2048
#define M_ROWS 8192
#define N_W 32         // W columns (only 24 used in H)
#define NC 24
#define KSPLIT 32
#define KRANGE (K_DIM / KSPLIT)   // 256 k per block
#define KSB 8                     // ksteps (of 32) per block
#define RPB 128                   // rows per block (8 tiles of 16)
#define THREADS 256               // 4 waves; wave handles 2 tiles

typedef short bf16x8 __attribute__((ext_vector_type(8)));
typedef float f32x4 __attribute__((ext_vector_type(4)));
union U32x4 { uint32_t u[4]; bf16x8 v; };

// wfrag (u16): [ks(256)][tile(2)][hilo(2)][lane(64)][e(8)] -> 1 MB total.
// Fragment (ks,tile,hilo) = contiguous 1KB; a block's 8-kstep slice = 32KB.
#define WFRAG_IDX(ks, tile, hilo) ((((ks) * 2 + (tile)) * 2 + (hilo)) * 64)

// ---------------------------------------------------------------------------
// Kernel 0: prepack W -> bf16 hi/lo B-fragments (once); zero Hsum.
// k-map matches A-frag map: lane=((k&31)>>3)*16+(n&15), e=k&7 (same perm both
// sides of the MFMA, so it cancels; only C/D layout matters).
// ---------------------------------------------------------------------------
__global__ __launch_bounds__(256) void mhc_prepack_kernel(
    const float* __restrict__ W, unsigned short* __restrict__ wfrag,
    float* __restrict__ Hsum)
{
    const int idx = blockIdx.x * 256 + threadIdx.x;   // 0 .. 262143
    const int k = idx >> 5, n = idx & 31;
    const float w = W[(size_t)k * N_W + n];
    const uint32_t u = __float_as_uint(w);
    const float hif = __uint_as_float(u & 0xFFFF0000u);
    const uint32_t ur = __float_as_uint(w - hif);

    const int ks = k >> 5, kk = k & 31;
    const int lane = ((kk >> 3) << 4) | (n & 15);
    const int e = kk & 7;
    const int tile = n >> 4;
    unsigned short* p = wfrag + ((size_t)WFRAG_IDX(ks, tile, 0) + lane) * 8 + e;
    p[0]   = (unsigned short)(u >> 16);    // hi  (hilo stride = 512 u16)
    p[512] = (unsigned short)(ur >> 16);   // lo

    if (idx < M_ROWS * NC) Hsum[idx] = 0.f;
}

// ---------------------------------------------------------------------------
// Kernel 1: partial H via MFMA, bf16 hi/lo split. H = Xhi@Whi+Xlo@Whi+Xhi@Wlo.
// Block = 256 thr (4 waves) x 128 rows x 256-k slice (blockIdx.y of 32).
// Stage the slice's 32KB wfrag into LDS ONCE (coalesced, 1 barrier) -> the
// K-loop's only global traffic is the X stream: per kstep 2x dwordx4 (X),
// 4x ds_read_b128 (B-frags), 6 MFMA. Wave wv does 16-row tiles {wv, wv+4},
// fully unrolled -> deep ILP, no further barriers. fp32 atomicAdd combine.
// C/D layout: D[row=(l>>4)*4+reg][col=l&15]  [HW-verified].
// ---------------------------------------------------------------------------
__global__ __launch_bounds__(THREADS, 4) void mhc_gemm_kernel(
    const float* __restrict__ X, const unsigned short* __restrict__ wfrag,
    float* __restrict__ Hsum)
{
    __shared__ __align__(16) unsigned short bfr[KSB][2][2][64][8];   // 32 KB
    const int t = threadIdx.x;
    const int l = t & 63;
    const int wv = t >> 6;
    const int rowbase = blockIdx.x * RPB;
    const int kbase = blockIdx.y * KRANGE;           // block's k origin

    // ---- stage this k-slice's B-fragments: 32KB contiguous, coalesced ----
    {
        const float4* __restrict__ src = reinterpret_cast<const float4*>(
            wfrag + (size_t)blockIdx.y * (KSB * 2 * 2 * 64 * 8));
        float4* dst = reinterpret_cast<float4*>(&bfr[0][0][0][0][0]);
#pragma unroll
        for (int q = 0; q < 8; ++q)
            dst[q * THREADS + t] = src[q * THREADS + t];
    }
    __syncthreads();

#pragma unroll
    for (int tt = 0; tt < 2; ++tt) {
        const int tile16 = wv + tt * 4;              // 0..7
        const int arow = rowbase + tile16 * 16 + (l & 15);
        const float* __restrict__ xp =
            X + (size_t)arow * K_DIM + kbase + ((l >> 4) << 3);

        f32x4 c0 = {0.f, 0.f, 0.f, 0.f};
        f32x4 c1 = {0.f, 0.f, 0.f, 0.f};

#pragma unroll
        for (int s = 0; s < KSB; ++s) {
            const float4 xa = *reinterpret_cast<const float4*>(xp + s * 32);
            const float4 xb = *reinterpret_cast<const float4*>(xp + s * 32 + 4);
            float xs[8];
            xs[0] = xa.x; xs[1] = xa.y; xs[2] = xa.z; xs[3] = xa.w;
            xs[4] = xb.x; xs[5] = xb.y; xs[6] = xb.z; xs[7] = xb.w;

            U32x4 ah, al;
#pragma unroll
            for (int p = 0; p < 4; ++p) {
                const uint32_t u0 = __float_as_uint(xs[2 * p]);
                const uint32_t u1 = __float_as_uint(xs[2 * p + 1]);
                const float h0 = __uint_as_float(u0 & 0xFFFF0000u);
                const float h1 = __uint_as_float(u1 & 0xFFFF0000u);
                const uint32_t r0 = __float_as_uint(xs[2 * p] - h0);
                const uint32_t r1 = __float_as_uint(xs[2 * p + 1] - h1);
                ah.u[p] = (u1 & 0xFFFF0000u) | (u0 >> 16);
                al.u[p] = (r1 & 0xFFFF0000u) | (r0 >> 16);
            }

            const bf16x8 bh0 = *reinterpret_cast<const bf16x8*>(&bfr[s][0][0][l][0]);
            const bf16x8 bl0 = *reinterpret_cast<const bf16x8*>(&bfr[s][0][1][l][0]);
            const bf16x8 bh1 = *reinterpret_cast<const bf16x8*>(&bfr[s][1][0][l][0]);
            const bf16x8 bl1 = *reinterpret_cast<const bf16x8*>(&bfr[s][1][1][l][0]);

            c0 = __builtin_amdgcn_mfma_f32_16x16x32_bf16(ah.v, bh0, c0, 0, 0, 0);
            c0 = __builtin_amdgcn_mfma_f32_16x16x32_bf16(al.v, bh0, c0, 0, 0, 0);
            c0 = __builtin_amdgcn_mfma_f32_16x16x32_bf16(ah.v, bl0, c0, 0, 0, 0);
            c1 = __builtin_amdgcn_mfma_f32_16x16x32_bf16(ah.v, bh1, c1, 0, 0, 0);
            c1 = __builtin_amdgcn_mfma_f32_16x16x32_bf16(al.v, bh1, c1, 0, 0, 0);
            c1 = __builtin_amdgcn_mfma_f32_16x16x32_bf16(ah.v, bl1, c1, 0, 0, 0);
        }

        // ---- combine: D[row=(l>>4)*4+r][col=l&15] ----
        const int drow = rowbase + tile16 * 16 + ((l >> 4) << 2);
        const int col = l & 15;
#pragma unroll
        for (int r = 0; r < 4; ++r)
            atomicAdd(&Hsum[(size_t)(drow + r) * NC + col], c0[r]);
        if (col < 8) {
#pragma unroll
            for (int r = 0; r < 4; ++r)
                atomicAdd(&Hsum[(size_t)(drow + r) * NC + 16 + col], c1[r]);
        }
    }
}

// ---------------------------------------------------------------------------
// Kernel 2: params (transform + sinkhorn) + apply. One block per row.
// ---------------------------------------------------------------------------
__global__ __launch_bounds__(256) void mhc_apply_kernel(
    const float* __restrict__ X, const float* __restrict__ Hsum,
    const float* __restrict__ ab, float* __restrict__ out)
{
    __shared__ float pbuf[NC];
    const int row = blockIdx.x;
    const int t = threadIdx.x;

    if (t < 64) {
        const int lane = t;
        const float pl = (lane < NC) ? Hsum[(size_t)row * NC + lane] : 0.f;
        const float bias  = (lane < NC) ? ab[lane] : 0.f;
        const float scale = ab[(lane < 16) ? 24 : ((lane < 20) ? 25 : 26)];

        float vout;
        if (lane < 16) {
            vout = __expf(fmaf(scale, pl, bias));                 // exp(a_res*H+b)
        } else {
            vout = fmaf(scale, 1.f / (1.f + __expf(-pl)), bias);  // a*sigmoid(H)+b
        }

        // Sinkhorn on lanes 0..15: lane = s*4 + i.
        float p = vout;
        for (int it = 0; it < 20; ++it) {
            float rs = p + __shfl_xor(p, 1);
            rs += __shfl_xor(rs, 2);
            p = p / rs;
            float cs = p + __shfl_xor(p, 4);
            cs += __shfl_xor(cs, 8);
            p = p / cs;
        }
        if (lane < NC) pbuf[lane] = (lane < 16) ? p : vout;
    }
    __syncthreads();

    float hres[4][4], hpre[4], hpos[4];
#pragma unroll
    for (int i = 0; i < 16; ++i) hres[i >> 2][i & 3] = pbuf[i];
#pragma unroll
    for (int i = 0; i < 4; ++i) hpre[i] = pbuf[16 + i];
#pragma unroll
    for (int i = 0; i < 4; ++i) hpos[i] = pbuf[20 + i];

    const float4* __restrict__ Xr =
        reinterpret_cast<const float4*>(X + (size_t)row * K_DIM);
    float4* __restrict__ Or = reinterpret_cast<float4*>(out + (size_t)row * K_DIM);

#pragma unroll
    for (int q = 0; q < 2; ++q) {
        const int pos = t + q * 256;          // float4 index within a 2048-seg
        float4 xq[4];
#pragma unroll
        for (int i = 0; i < 4; ++i) xq[i] = Xr[i * (D_DIM / 4) + pos];

        float y[4];
#pragma unroll
        for (int e = 0; e < 4; ++e) {
            float s = 0.f;
#pragma unroll
            for (int i = 0; i < 4; ++i)
                s = fmaf(hpre[i], reinterpret_cast<const float*>(&xq[i])[e], s);
            y[e] = s;
        }

#pragma unroll
        for (int s = 0; s < 4; ++s) {
            float4 o;
            float* oe = reinterpret_cast<float*>(&o);
#pragma unroll
            for (int e = 0; e < 4; ++e) {
                float v = hpos[s] * y[e];
#pragma unroll
                for (int i = 0; i < 4; ++i)
                    v = fmaf(hres[s][i], reinterpret_cast<const float*>(&xq[i])[e], v);
                oe[e] = v;
            }
            Or[s * (D_DIM / 4) + pos] = o;
        }
    }
}

extern "C" void kernel_launch(void* const* d_in, const int* in_sizes, int n_in,
                              void* d_out, int out_size, void* d_ws, size_t ws_size,
                              hipStream_t stream) {
    const float* X  = (const float*)d_in[0];
    const float* W  = (const float*)d_in[1];
    const float* ab = (const float*)d_in[2];
    float* out = (float*)d_out;
    unsigned short* wfrag = (unsigned short*)d_ws;          // 1,048,576 B
    float* Hsum = (float*)((char*)d_ws + 1048576);          // + 786,432 B

    mhc_prepack_kernel<<<(K_DIM * N_W) / 256, 256, 0, stream>>>(W, wfrag, Hsum);
    dim3 g1(M_ROWS / RPB, KSPLIT);
    mhc_gemm_kernel<<<g1, THREADS, 0, stream>>>(X, wfrag, Hsum);
    mhc_apply_kernel<<<M_ROWS, 256, 0, stream>>>(X, Hsum, ab, out);
}